// Round 16
// baseline (119.618 us; speedup 1.0000x reference)
//
#include <hip/hip_runtime.h>
#include <hip/hip_bf16.h>

#define N_ 16
#define L_ 256
#define C_ 512
#define HW_ 1024
#define HEADS_ 16
#define DH_ 32

typedef unsigned short u16;
typedef unsigned int u32;
typedef __attribute__((ext_vector_type(8))) short short8_t;
typedef __attribute__((ext_vector_type(4))) float f32x4;

__device__ __forceinline__ u16 f2bs(float f) {
    union { float f; u32 i; } x; x.f = f;
    u32 r = x.i + 0x7fffu + ((x.i >> 16) & 1u);
    return (u16)(r >> 16);
}
__device__ __forceinline__ u32 cvt_pk_bf16(float lo, float hi) {
    u32 r;
    asm("v_cvt_pk_bf16_f32 %0, %1, %2" : "=v"(r) : "v"(lo), "v"(hi));
    return r;
}
__device__ __forceinline__ void cvt8(const float* __restrict__ src, void* dst) {
    float4 lo = *(const float4*)src;
    float4 hi = *(const float4*)(src + 4);
    union { u32 w[4]; short8_t v; } pk;
    pk.w[0] = cvt_pk_bf16(lo.x, lo.y);
    pk.w[1] = cvt_pk_bf16(lo.z, lo.w);
    pk.w[2] = cvt_pk_bf16(hi.x, hi.y);
    pk.w[3] = cvt_pk_bf16(hi.z, hi.w);
    *(short8_t*)dst = pk.v;
}
#define AS1(p) (const __attribute__((address_space(1))) void*)(p)
#define AS3(p) (__attribute__((address_space(3))) void*)(p)

// ---------------------------------------------------------------------------
// prep (R15-verified, byte-identical): blocks [0,256) KV-GEMM from raw fp32;
// blocks [256,2304) feature -> Ftb [(n*HW+pos)][c] bf16 transpose.
// ---------------------------------------------------------------------------
__global__ __launch_bounds__(256) void prep_kernel(
    const float* __restrict__ feature, const float* __restrict__ token,
    const float* __restrict__ wk, const float* __restrict__ wv,
    const float* __restrict__ bk, const float* __restrict__ bv,
    u16* __restrict__ Ftb, u16* __restrict__ Kout, u16* __restrict__ Vt)
{
    __shared__ __align__(16) unsigned char smem[32768];
    const int t = threadIdx.x;

    if (blockIdx.x < 256) {
        const int kvid = blockIdx.x;
        const int xcd = kvid & 7, j = kvid >> 3;
        const int m0 = (xcd * 4 + (j & 3)) * 128;
        const int n0 = (j >> 2) * 64;
        const int lane = t & 63, wid = t >> 6;
        const int i16 = lane & 15, g = lane >> 4;
        const int wm = wid >> 1, wn = wid & 1;
        const int r8 = t >> 3, c8 = t & 7;
        u16* Tok = (u16*)smem;
        u16* Bk  = (u16*)(smem + 16384);
        u16* Bv  = (u16*)(smem + 24576);
        u16 (*LTo)[72] = (u16(*)[72])smem;

        f32x4 ak[4][2], av[4][2];
        #pragma unroll
        for (int mt = 0; mt < 4; ++mt)
            #pragma unroll
            for (int nt = 0; nt < 2; ++nt) {
                ak[mt][nt] = (f32x4){0.f, 0.f, 0.f, 0.f};
                av[mt][nt] = (f32x4){0.f, 0.f, 0.f, 0.f};
            }

        for (int c0 = 0; c0 < C_; c0 += 64) {
            __syncthreads();
            #pragma unroll
            for (int p = 0; p < 4; ++p) {
                const int m = p * 32 + r8;
                cvt8(&token[(size_t)(m0 + m) * C_ + c0 + c8 * 8],
                     &Tok[m * 64 + ((c8 ^ (m & 7)) << 3)]);
            }
            #pragma unroll
            for (int p = 0; p < 2; ++p) {
                const int m = p * 32 + r8;
                const int sw = m * 64 + ((c8 ^ (m & 7)) << 3);
                cvt8(&wk[(size_t)(n0 + m) * C_ + c0 + c8 * 8], &Bk[sw]);
                cvt8(&wv[(size_t)(n0 + m) * C_ + c0 + c8 * 8], &Bv[sw]);
            }
            __syncthreads();
            #pragma unroll
            for (int ks = 0; ks < 2; ++ks) {
                short8_t a[4], bbk[2], bbv[2];
                #pragma unroll
                for (int mt = 0; mt < 4; ++mt) {
                    const int m = wm * 64 + mt * 16 + i16;
                    a[mt] = *(const short8_t*)&Tok[m * 64 + ((((ks << 2) | g) ^ (m & 7)) << 3)];
                }
                #pragma unroll
                for (int nt = 0; nt < 2; ++nt) {
                    const int d = wn * 32 + nt * 16 + i16;
                    const int sw = d * 64 + ((((ks << 2) | g) ^ (d & 7)) << 3);
                    bbk[nt] = *(const short8_t*)&Bk[sw];
                    bbv[nt] = *(const short8_t*)&Bv[sw];
                }
                #pragma unroll
                for (int mt = 0; mt < 4; ++mt)
                    #pragma unroll
                    for (int nt = 0; nt < 2; ++nt) {
                        ak[mt][nt] = __builtin_amdgcn_mfma_f32_16x16x32_bf16(
                            a[mt], bbk[nt], ak[mt][nt], 0, 0, 0);
                        av[mt][nt] = __builtin_amdgcn_mfma_f32_16x16x32_bf16(
                            a[mt], bbv[nt], av[mt][nt], 0, 0, 0);
                    }
            }
        }
        const int nb = m0 >> 8, l0 = m0 & 255;
        const size_t vtbase = (size_t)nb * C_ * L_;
        #pragma unroll
        for (int nt = 0; nt < 2; ++nt) {
            const int d = n0 + wn * 32 + nt * 16 + i16;
            const float bb = bv[d];
            #pragma unroll
            for (int mt = 0; mt < 4; ++mt) {
                ushort4 w;
                w.x = f2bs(av[mt][nt][0] + bb);
                w.y = f2bs(av[mt][nt][1] + bb);
                w.z = f2bs(av[mt][nt][2] + bb);
                w.w = f2bs(av[mt][nt][3] + bb);
                const int l = l0 + wm * 64 + mt * 16 + g * 4;
                *(ushort4*)&Vt[vtbase + (size_t)d * L_ + l] = w;
            }
        }
        __syncthreads();
        #pragma unroll
        for (int nt = 0; nt < 2; ++nt) {
            const int col = wn * 32 + nt * 16 + i16;
            const float bb = bk[n0 + col];
            #pragma unroll
            for (int mt = 0; mt < 4; ++mt)
                #pragma unroll
                for (int r = 0; r < 4; ++r)
                    LTo[wm * 64 + mt * 16 + g * 4 + r][col] = f2bs(ak[mt][nt][r] + bb);
        }
        __syncthreads();
        #pragma unroll
        for (int rep = 0; rep < 4; ++rep) {
            const int m = (t >> 3) + rep * 32;
            const int cs2 = (t & 7) * 8;
            *(short8_t*)&Kout[(size_t)(m0 + m) * C_ + n0 + cs2] = *(short8_t*)&LTo[m][cs2];
        }
    } else {
        float (*LT)[67] = (float(*)[67])smem;
        const int tidx = blockIdx.x - 256;
        const int pb = tidx & 15, cb = (tidx >> 4) & 7, n = tidx >> 7;
        const int c0 = cb * 64, pos0 = pb * 64;

        #pragma unroll
        for (int r = 0; r < 4; ++r) {
            const int c = r * 16 + (t >> 4);
            const int p = (t & 15) * 4;
            float4 v = *(const float4*)&feature[
                ((size_t)n * C_ + c0 + c) * HW_ + pos0 + p];
            LT[c][p] = v.x; LT[c][p+1] = v.y; LT[c][p+2] = v.z; LT[c][p+3] = v.w;
        }
        __syncthreads();
        #pragma unroll
        for (int rep = 0; rep < 2; ++rep) {
            const int pos = (t >> 3) + rep * 32;
            const int c = (t & 7) * 8;
            u16 tmp[8];
            #pragma unroll
            for (int j = 0; j < 8; ++j) tmp[j] = f2bs(LT[c + j][pos]);
            *(short8_t*)&Ftb[(size_t)(n * HW_ + pos0 + pos) * C_ + c0 + c] =
                *(short8_t*)tmp;
        }
    }
}

// ---------------------------------------------------------------------------
// fattn4: fused Q-projection + attention, FOUR heads per block.
//  Block = (tile 0..255) x (head-quad 0..3).  1024 blocks.
//  Phase 0: 8 K-steps dbuf 2x24K: Ftb tile [64pos][64c] (gload_lds) +
//    wq slab [128d][64c] (fp32, coalesced, cvt8); per wave 16 MFMA/step ->
//    aq[2*hh(+1)] = Q[pos][d] for heads hq*4+hh.
//  Head loop (unrolled x4): shfl handoff -> bq frag; stage K_h/V_h into dead
//    phase-0 LDS; verified attn v2.1 body; per-head epilogue.
// LDS 48K -> 3 blocks/CU.
// ---------------------------------------------------------------------------
__global__ __launch_bounds__(256) void fattn_kernel(
    const float* __restrict__ feature, const u16* __restrict__ Ftb,
    const float* __restrict__ wq, const float* __restrict__ bqv,
    const u16* __restrict__ Kws, const u16* __restrict__ Vws,
    float* __restrict__ out)
{
    __shared__ __align__(16) unsigned char smem[49152];
    const u32 QB = 24576;   // per-buffer: [0,8K) Ftb tile, [8K,24K) wq slab

    const int t = threadIdx.x;
    const int wid = t >> 6, lane = t & 63;
    const int i16 = lane & 15, g = lane >> 4;
    const int hq = blockIdx.x & 3;
    const int tile = blockIdx.x >> 2;
    const int n = tile >> 4, pt = tile & 15;
    const int pos0 = pt * 64;
    const size_t fbase = (size_t)(n * HW_ + pos0) * C_;
    const int q = wid * 16 + i16;
    const int r8 = t >> 3, gr = t & 7;

    // ---------------- Phase 0: Q projection for 4 heads ----------------
    f32x4 aq[8];
    #pragma unroll
    for (int i = 0; i < 8; ++i) aq[i] = (f32x4){0.f, 0.f, 0.f, 0.f};

    #define FQ_STAGE(buf, c0) { \
        _Pragma("unroll") \
        for (int p = 0; p < 2; ++p) { \
            const int row = p * 32 + r8; \
            __builtin_amdgcn_global_load_lds( \
                AS1(Ftb + fbase + (size_t)row * C_ + (c0) + ((gr ^ (row & 7)) << 3)), \
                AS3(smem + (buf) * QB + (p * 32 + wid * 8) * 128), 16, 0, 0); } \
        { \
            const int wrow = t >> 1; \
            const int cb0 = (t & 1) * 4; \
            _Pragma("unroll") \
            for (int cc = 0; cc < 4; ++cc) { \
                const int c8 = cb0 + cc; \
                float wf[8]; \
                const float* wsrc = wq + (size_t)(hq * 128 + wrow) * C_ + (c0) + c8 * 8; \
                *(float4*)&wf[0] = *(const float4*)&wsrc[0]; \
                *(float4*)&wf[4] = *(const float4*)&wsrc[4]; \
                cvt8(wf, smem + (buf) * QB + 8192 + \
                     (u32)(wrow * 128 + ((c8 ^ (wrow & 7)) << 4))); \
            } \
        } }

    FQ_STAGE(0, 0);
    __syncthreads();
    #pragma unroll
    for (int cs = 0; cs < 8; ++cs) {
        const int cur = cs & 1;
        if (cs < 7) FQ_STAGE(cur ^ 1, (cs + 1) * 64);
        #pragma unroll
        for (int ks = 0; ks < 2; ++ks) {
            const int browq = wid * 16 + i16;
            short8_t b = *(const short8_t*)(smem + cur * QB +
                (u32)(browq * 128 + ((((ks << 2) | g) ^ (browq & 7)) << 4)));
            const u32 gsw = (u32)((((ks << 2) | g) ^ (i16 & 7)) << 4);
            #pragma unroll
            for (int hh = 0; hh < 4; ++hh) {
                short8_t a0 = *(const short8_t*)(smem + cur * QB + 8192 +
                    (u32)((hh * 32 + i16) * 128) + gsw);
                short8_t a1 = *(const short8_t*)(smem + cur * QB + 8192 +
                    (u32)((hh * 32 + 16 + i16) * 128) + gsw);
                aq[2 * hh]     = __builtin_amdgcn_mfma_f32_16x16x32_bf16(a0, b, aq[2 * hh], 0, 0, 0);
                aq[2 * hh + 1] = __builtin_amdgcn_mfma_f32_16x16x32_bf16(a1, b, aq[2 * hh + 1], 0, 0, 0);
            }
        }
        __syncthreads();
    }

    // ---------------- head loop ----------------
    const float K2 = 0.25506288f;  // log2(e) / sqrt(32)
    const int e7 = i16 & 7;
    const int kgr = g ^ ((i16 >> 1) & 3);

    #pragma unroll
    for (int h2 = 0; h2 < 4; ++h2) {
        const int h = hq * 4 + h2;
        const size_t kbase = ((size_t)n * L_) * C_ + h * DH_;
        const size_t vbase = (size_t)n * C_ * L_ + (size_t)h * DH_ * L_;

        // handoff: D-frags -> QK^T B-frag (R8/R15-verified)
        short8_t bq;
        {
            float4 b0 = *(const float4*)&bqv[h * 32 + g * 4];
            float4 b1 = *(const float4*)&bqv[h * 32 + 16 + g * 4];
            u32 A0 = cvt_pk_bf16(aq[2 * h2][0] + b0.x, aq[2 * h2][1] + b0.y);
            u32 A1 = cvt_pk_bf16(aq[2 * h2][2] + b0.z, aq[2 * h2][3] + b0.w);
            u32 B0 = cvt_pk_bf16(aq[2 * h2 + 1][0] + b1.x, aq[2 * h2 + 1][1] + b1.y);
            u32 B1 = cvt_pk_bf16(aq[2 * h2 + 1][2] + b1.z, aq[2 * h2 + 1][3] + b1.w);
            const int srcLo = ((g & 1) * 2) * 16 + i16;
            const int srcHi = srcLo + 16;
            u32 XA0 = (u32)__shfl((int)A0, srcLo), XA1 = (u32)__shfl((int)A1, srcLo);
            u32 XA2 = (u32)__shfl((int)A0, srcHi), XA3 = (u32)__shfl((int)A1, srcHi);
            u32 XB0 = (u32)__shfl((int)B0, srcLo), XB1 = (u32)__shfl((int)B1, srcLo);
            u32 XB2 = (u32)__shfl((int)B0, srcHi), XB3 = (u32)__shfl((int)B1, srcHi);
            union { u32 w[4]; short8_t v; } bp;
            bp.w[0] = g < 2 ? XA0 : XB0;
            bp.w[1] = g < 2 ? XA1 : XB1;
            bp.w[2] = g < 2 ? XA2 : XB2;
            bp.w[3] = g < 2 ? XA3 : XB3;
            bq = bp.v;
        }

        __syncthreads();   // previous head's P/V reads (or phase-0 bufs) done
        // stage K/V for this head
        #pragma unroll
        for (int p = 0; p < 4; ++p) {
            const int kg = (lane & 3) ^ ((lane >> 3) & 3);
            const int kr = wid * 64 + p * 16 + (lane >> 2);
            const u16* ksrc = Kws + kbase + (size_t)kr * C_ + kg * 8;
            __builtin_amdgcn_global_load_lds(AS1(ksrc),
                AS3(smem + wid * 4096 + p * 1024), 16, 0, 0);
            const int vd = wid * 8 + p * 2 + (lane >> 5);
            const u16* vsrc = Vws + vbase + (size_t)vd * L_ + ((lane & 31) ^ (vd & 7)) * 8;
            __builtin_amdgcn_global_load_lds(AS1(vsrc),
                AS3(smem + 16384 + wid * 4096 + p * 1024), 16, 0, 0);
        }
        __syncthreads();

        // swapped QK^T
        f32x4 s[16];
        #pragma unroll
        for (int nf = 0; nf < 16; ++nf) {
            short8_t a = *(const short8_t*)(smem + (nf * 16 + i16) * 64 + kgr * 16);
            f32x4 z = {0.f, 0.f, 0.f, 0.f};
            s[nf] = __builtin_amdgcn_mfma_f32_16x16x32_bf16(a, bq, z, 0, 0, 0);
        }

        float mm[16], sm[16];
        #pragma unroll
        for (int nf = 0; nf < 16; ++nf)
            mm[nf] = fmaxf(fmaxf(s[nf][0], s[nf][1]), fmaxf(s[nf][2], s[nf][3]));
        #pragma unroll
        for (int st = 8; st >= 1; st >>= 1)
            #pragma unroll
            for (int i = 0; i < 8; ++i)
                if (i < st) mm[i] = fmaxf(mm[i], mm[i + st]);
        float m = mm[0];
        m = fmaxf(m, __shfl_xor(m, 16));
        m = fmaxf(m, __shfl_xor(m, 32));

        #pragma unroll
        for (int nf = 0; nf < 16; ++nf) {
            #pragma unroll
            for (int r = 0; r < 4; ++r) s[nf][r] = exp2f((s[nf][r] - m) * K2);
            sm[nf] = (s[nf][0] + s[nf][1]) + (s[nf][2] + s[nf][3]);
        }
        #pragma unroll
        for (int st = 8; st >= 1; st >>= 1)
            #pragma unroll
            for (int i = 0; i < 8; ++i)
                if (i < st) sm[i] += sm[i + st];
        float ssum = sm[0];
        ssum += __shfl_xor(ssum, 16);
        ssum += __shfl_xor(ssum, 32);
        const float pinv = 1.0f / ssum;

        __syncthreads();  // K dead -> P may alias

        f32x4 o0 = {0.f, 0.f, 0.f, 0.f}, o1 = {0.f, 0.f, 0.f, 0.f};

        #pragma unroll
        for (int hb = 0; hb < 2; ++hb) {
            #pragma unroll
            for (int nfp = 0; nfp < 8; ++nfp) {
                const int nf = hb * 8 + nfp;
                #pragma unroll
                for (int w = 0; w < 2; ++w) {
                    u32 pw = cvt_pk_bf16(s[nf][2 * w] * pinv, s[nf][2 * w + 1] * pinv);
                    const int gran = (nfp * 2 + (g >> 1)) ^ e7;
                    *(u32*)(smem + q * 256 + gran * 16 + ((g & 1) * 2 + w) * 4) = pw;
                }
            }
            __syncthreads();
            #pragma unroll
            for (int ks = 0; ks < 4; ++ks) {
                short8_t pb = *(const short8_t*)(smem + q * 256 + (((ks * 4 + g) ^ e7) * 16));
                const int vg = (((hb * 4 + ks) * 4 + g) ^ e7) * 16;
                short8_t va0 = *(const short8_t*)(smem + 16384 + i16 * 512 + vg);
                short8_t va1 = *(const short8_t*)(smem + 16384 + (16 + i16) * 512 + vg);
                o0 = __builtin_amdgcn_mfma_f32_16x16x32_bf16(va0, pb, o0, 0, 0, 0);
                o1 = __builtin_amdgcn_mfma_f32_16x16x32_bf16(va1, pb, o1, 0, 0, 0);
            }
            if (hb == 0) __syncthreads();
        }

        // epilogue for this head
        const size_t obase = ((size_t)n * C_ + h * DH_) * HW_ + pos0 + q;
        #pragma unroll
        for (int r = 0; r < 4; ++r) {
            const size_t oa = obase + (size_t)(g * 4 + r) * HW_;
            out[oa] = feature[oa] + o0[r];
            const size_t ob = obase + (size_t)(16 + g * 4 + r) * HW_;
            out[ob] = feature[ob] + o1[r];
        }
    }
}

extern "C" void kernel_launch(void* const* d_in, const int* in_sizes, int n_in,
                              void* d_out, int out_size, void* d_ws, size_t ws_size,
                              hipStream_t stream)
{
    const float* feature = (const float*)d_in[0];
    const float* token   = (const float*)d_in[1];
    const float* wq      = (const float*)d_in[2];
    const float* bq      = (const float*)d_in[3];
    const float* wk      = (const float*)d_in[4];
    const float* bk      = (const float*)d_in[5];
    const float* wv      = (const float*)d_in[6];
    const float* bv      = (const float*)d_in[7];
    float* out = (float*)d_out;

    // d_ws (24 MiB): [0,16M) Ftb bf16 | [16M,20M) K | [20M,24M) V^T
    u16* Ftb = (u16*)d_ws;
    u16* Kws = Ftb + (size_t)N_ * HW_ * C_;
    u16* Vws = Kws + (size_t)N_ * L_ * C_;

    prep_kernel<<<dim3(2304), 256, 0, stream>>>(feature, token, wk, wv,
                                                bk, bv, Ftb, Kws, Vws);
    fattn_kernel<<<dim3(1024), 256, 0, stream>>>(feature, Ftb, wq, bq,
                                                 Kws, Vws, out);
}

// Round 17
// 73.076 us; speedup vs baseline: 1.6369x; 1.6369x over previous
//
#include <hip/hip_runtime.h>
#include <hip/hip_bf16.h>

#define N_ 16
#define L_ 256
#define C_ 512
#define HW_ 1024
#define HEADS_ 16
#define DH_ 32

typedef unsigned short u16;
typedef unsigned int u32;
typedef __attribute__((ext_vector_type(8))) short short8_t;
typedef __attribute__((ext_vector_type(4))) float f32x4;

__device__ __forceinline__ u16 f2bs(float f) {
    union { float f; u32 i; } x; x.f = f;
    u32 r = x.i + 0x7fffu + ((x.i >> 16) & 1u);
    return (u16)(r >> 16);
}
__device__ __forceinline__ u32 cvt_pk_bf16(float lo, float hi) {
    u32 r;
    asm("v_cvt_pk_bf16_f32 %0, %1, %2" : "=v"(r) : "v"(lo), "v"(hi));
    return r;
}
__device__ __forceinline__ void cvt8(const float* __restrict__ src, void* dst) {
    float4 lo = *(const float4*)src;
    float4 hi = *(const float4*)(src + 4);
    union { u32 w[4]; short8_t v; } pk;
    pk.w[0] = cvt_pk_bf16(lo.x, lo.y);
    pk.w[1] = cvt_pk_bf16(lo.z, lo.w);
    pk.w[2] = cvt_pk_bf16(hi.x, hi.y);
    pk.w[3] = cvt_pk_bf16(hi.z, hi.w);
    *(short8_t*)dst = pk.v;
}
#define AS1(p) (const __attribute__((address_space(1))) void*)(p)
#define AS3(p) (__attribute__((address_space(3))) void*)(p)

// ---------------------------------------------------------------------------
// prep: blocks [0,256): KV-GEMM 128l x 64d from RAW fp32 (verified R14/R15);
//       blocks [256,2304): feature -> Ftb [(n*HW+pos)][c] bf16 (verified);
//       blocks [2304,2560): wq fp32 -> wqb bf16 flat convert.
// KV first so its long blocks overlap the BW-bound transpose.
// ---------------------------------------------------------------------------
__global__ __launch_bounds__(256) void prep_kernel(
    const float* __restrict__ feature, const float* __restrict__ token,
    const float* __restrict__ wq, const float* __restrict__ wk,
    const float* __restrict__ wv, const float* __restrict__ bk,
    const float* __restrict__ bv,
    u16* __restrict__ Ftb, u16* __restrict__ wqb,
    u16* __restrict__ Kout, u16* __restrict__ Vt)
{
    __shared__ __align__(16) unsigned char smem[32768];
    const int t = threadIdx.x;

    if (blockIdx.x < 256) {
        // ---------------- KV path (verified) ----------------
        const int kvid = blockIdx.x;
        const int xcd = kvid & 7, j = kvid >> 3;
        const int m0 = (xcd * 4 + (j & 3)) * 128;
        const int n0 = (j >> 2) * 64;
        const int lane = t & 63, wid = t >> 6;
        const int i16 = lane & 15, g = lane >> 4;
        const int wm = wid >> 1, wn = wid & 1;
        const int r8 = t >> 3, c8 = t & 7;
        u16* Tok = (u16*)smem;
        u16* Bk  = (u16*)(smem + 16384);
        u16* Bv  = (u16*)(smem + 24576);
        u16 (*LTo)[72] = (u16(*)[72])smem;

        f32x4 ak[4][2], av[4][2];
        #pragma unroll
        for (int mt = 0; mt < 4; ++mt)
            #pragma unroll
            for (int nt = 0; nt < 2; ++nt) {
                ak[mt][nt] = (f32x4){0.f, 0.f, 0.f, 0.f};
                av[mt][nt] = (f32x4){0.f, 0.f, 0.f, 0.f};
            }

        for (int c0 = 0; c0 < C_; c0 += 64) {
            __syncthreads();
            #pragma unroll
            for (int p = 0; p < 4; ++p) {
                const int m = p * 32 + r8;
                cvt8(&token[(size_t)(m0 + m) * C_ + c0 + c8 * 8],
                     &Tok[m * 64 + ((c8 ^ (m & 7)) << 3)]);
            }
            #pragma unroll
            for (int p = 0; p < 2; ++p) {
                const int m = p * 32 + r8;
                const int sw = m * 64 + ((c8 ^ (m & 7)) << 3);
                cvt8(&wk[(size_t)(n0 + m) * C_ + c0 + c8 * 8], &Bk[sw]);
                cvt8(&wv[(size_t)(n0 + m) * C_ + c0 + c8 * 8], &Bv[sw]);
            }
            __syncthreads();
            #pragma unroll
            for (int ks = 0; ks < 2; ++ks) {
                short8_t a[4], bbk[2], bbv[2];
                #pragma unroll
                for (int mt = 0; mt < 4; ++mt) {
                    const int m = wm * 64 + mt * 16 + i16;
                    a[mt] = *(const short8_t*)&Tok[m * 64 + ((((ks << 2) | g) ^ (m & 7)) << 3)];
                }
                #pragma unroll
                for (int nt = 0; nt < 2; ++nt) {
                    const int d = wn * 32 + nt * 16 + i16;
                    const int sw = d * 64 + ((((ks << 2) | g) ^ (d & 7)) << 3);
                    bbk[nt] = *(const short8_t*)&Bk[sw];
                    bbv[nt] = *(const short8_t*)&Bv[sw];
                }
                #pragma unroll
                for (int mt = 0; mt < 4; ++mt)
                    #pragma unroll
                    for (int nt = 0; nt < 2; ++nt) {
                        ak[mt][nt] = __builtin_amdgcn_mfma_f32_16x16x32_bf16(
                            a[mt], bbk[nt], ak[mt][nt], 0, 0, 0);
                        av[mt][nt] = __builtin_amdgcn_mfma_f32_16x16x32_bf16(
                            a[mt], bbv[nt], av[mt][nt], 0, 0, 0);
                    }
            }
        }
        const int nb = m0 >> 8, l0 = m0 & 255;
        const size_t vtbase = (size_t)nb * C_ * L_;
        #pragma unroll
        for (int nt = 0; nt < 2; ++nt) {
            const int d = n0 + wn * 32 + nt * 16 + i16;
            const float bb = bv[d];
            #pragma unroll
            for (int mt = 0; mt < 4; ++mt) {
                ushort4 w;
                w.x = f2bs(av[mt][nt][0] + bb);
                w.y = f2bs(av[mt][nt][1] + bb);
                w.z = f2bs(av[mt][nt][2] + bb);
                w.w = f2bs(av[mt][nt][3] + bb);
                const int l = l0 + wm * 64 + mt * 16 + g * 4;
                *(ushort4*)&Vt[vtbase + (size_t)d * L_ + l] = w;
            }
        }
        __syncthreads();
        #pragma unroll
        for (int nt = 0; nt < 2; ++nt) {
            const int col = wn * 32 + nt * 16 + i16;
            const float bb = bk[n0 + col];
            #pragma unroll
            for (int mt = 0; mt < 4; ++mt)
                #pragma unroll
                for (int r = 0; r < 4; ++r)
                    LTo[wm * 64 + mt * 16 + g * 4 + r][col] = f2bs(ak[mt][nt][r] + bb);
        }
        __syncthreads();
        #pragma unroll
        for (int rep = 0; rep < 4; ++rep) {
            const int m = (t >> 3) + rep * 32;
            const int cs2 = (t & 7) * 8;
            *(short8_t*)&Kout[(size_t)(m0 + m) * C_ + n0 + cs2] = *(short8_t*)&LTo[m][cs2];
        }
    } else if (blockIdx.x < 2304) {
        // ---------------- feature transpose (verified) ----------------
        float (*LT)[67] = (float(*)[67])smem;
        const int tidx = blockIdx.x - 256;
        const int pb = tidx & 15, cb = (tidx >> 4) & 7, n = tidx >> 7;
        const int c0 = cb * 64, pos0 = pb * 64;

        #pragma unroll
        for (int r = 0; r < 4; ++r) {
            const int c = r * 16 + (t >> 4);
            const int p = (t & 15) * 4;
            float4 v = *(const float4*)&feature[
                ((size_t)n * C_ + c0 + c) * HW_ + pos0 + p];
            LT[c][p] = v.x; LT[c][p+1] = v.y; LT[c][p+2] = v.z; LT[c][p+3] = v.w;
        }
        __syncthreads();
        #pragma unroll
        for (int rep = 0; rep < 2; ++rep) {
            const int pos = (t >> 3) + rep * 32;
            const int c = (t & 7) * 8;
            u16 tmp[8];
            #pragma unroll
            for (int j = 0; j < 8; ++j) tmp[j] = f2bs(LT[c + j][pos]);
            *(short8_t*)&Ftb[(size_t)(n * HW_ + pos0 + pos) * C_ + c0 + c] =
                *(short8_t*)tmp;
        }
    } else {
        // ---------------- wq flat convert ----------------
        const int idx = (blockIdx.x - 2304) * 256 + t;
        float4 v = ((const float4*)wq)[idx];
        ushort4 w;
        w.x = f2bs(v.x); w.y = f2bs(v.y); w.z = f2bs(v.z); w.w = f2bs(v.w);
        ((ushort4*)wqb)[idx] = w;
    }
}

// ---------------------------------------------------------------------------
// gemm_q (R12's Q path verbatim, standalone for clean counters):
// 128pos x 64d Ftb GEMM, 32KB single buffer, KV-style gload_lds staging,
// LDS-bounce epilogue. 1024 blocks (~5 blocks/CU co-resident).
// ---------------------------------------------------------------------------
__global__ __launch_bounds__(256) void gemm_q_kernel(
    const u16* __restrict__ Ftb, const u16* __restrict__ wqb,
    const float* __restrict__ bq, u16* __restrict__ Qout)
{
    __shared__ __align__(16) unsigned char smem[32768];

    const int t = threadIdx.x;
    const int lane = t & 63, wid = t >> 6;
    const int i16 = lane & 15, g = lane >> 4;
    const int wm = wid >> 1, wn = wid & 1;
    const int r8 = t >> 3, gr = t & 7;

    const int qid = blockIdx.x;
    const int xcd = qid & 7, j = qid >> 3;
    const int m0 = (xcd * 16 + (j & 15)) * 128;
    const int n0 = (j >> 4) * 64;
    u16* Ft = (u16*)smem;
    u16* Bq = (u16*)(smem + 16384);
    u16 (*LTo)[72] = (u16(*)[72])smem;

    f32x4 aq[4][2];
    #pragma unroll
    for (int mt = 0; mt < 4; ++mt)
        #pragma unroll
        for (int nt = 0; nt < 2; ++nt)
            aq[mt][nt] = (f32x4){0.f, 0.f, 0.f, 0.f};

    for (int c0 = 0; c0 < C_; c0 += 64) {
        __syncthreads();
        #pragma unroll
        for (int p = 0; p < 4; ++p) {
            const int row = p * 32 + r8;
            __builtin_amdgcn_global_load_lds(
                AS1(Ftb + (size_t)(m0 + row) * C_ + c0 + ((gr ^ (row & 7)) << 3)),
                AS3(smem + (p * 32 + wid * 8) * 128), 16, 0, 0);
        }
        #pragma unroll
        for (int p = 0; p < 2; ++p) {
            const int row = p * 32 + r8;
            __builtin_amdgcn_global_load_lds(
                AS1(wqb + (size_t)(n0 + row) * C_ + c0 + ((gr ^ (row & 7)) << 3)),
                AS3(smem + 16384 + (p * 32 + wid * 8) * 128), 16, 0, 0);
        }
        __syncthreads();
        #pragma unroll
        for (int ks = 0; ks < 2; ++ks) {
            short8_t a[4], b[2];
            #pragma unroll
            for (int mt = 0; mt < 4; ++mt) {
                const int m = wm * 64 + mt * 16 + i16;
                a[mt] = *(const short8_t*)&Ft[m * 64 + ((((ks << 2) | g) ^ (m & 7)) << 3)];
            }
            #pragma unroll
            for (int nt = 0; nt < 2; ++nt) {
                const int d = wn * 32 + nt * 16 + i16;
                b[nt] = *(const short8_t*)&Bq[d * 64 + ((((ks << 2) | g) ^ (d & 7)) << 3)];
            }
            #pragma unroll
            for (int mt = 0; mt < 4; ++mt)
                #pragma unroll
                for (int nt = 0; nt < 2; ++nt)
                    aq[mt][nt] = __builtin_amdgcn_mfma_f32_16x16x32_bf16(
                        a[mt], b[nt], aq[mt][nt], 0, 0, 0);
        }
    }
    __syncthreads();
    #pragma unroll
    for (int nt = 0; nt < 2; ++nt) {
        const int col = wn * 32 + nt * 16 + i16;
        const float bb = bq[n0 + col];
        #pragma unroll
        for (int mt = 0; mt < 4; ++mt)
            #pragma unroll
            for (int r = 0; r < 4; ++r)
                LTo[wm * 64 + mt * 16 + g * 4 + r][col] = f2bs(aq[mt][nt][r] + bb);
    }
    __syncthreads();
    #pragma unroll
    for (int rep = 0; rep < 4; ++rep) {
        const int m = (t >> 3) + rep * 32;
        const int cs = (t & 7) * 8;
        *(short8_t*)&Qout[(size_t)(m0 + m) * C_ + n0 + cs] = *(short8_t*)&LTo[m][cs];
    }
}

// ---------------------------------------------------------------------------
// attn v2.1 (verified, byte-identical).
// ---------------------------------------------------------------------------
__global__ __launch_bounds__(256) void attn_kernel(
    const u16* __restrict__ Qws, const u16* __restrict__ Kws,
    const u16* __restrict__ Vws, const float* __restrict__ feature,
    float* __restrict__ out)
{
    __shared__ __align__(16) unsigned char smem[32768];

    const int t = threadIdx.x;
    const int wid = t >> 6, lane = t & 63;
    const int i16 = lane & 15, g = lane >> 4;
    const int pt = blockIdx.x, h = blockIdx.y, n = blockIdx.z;
    const int pos0 = pt * 64;
    const size_t qbase = ((size_t)n * HW_ + pos0) * C_ + h * DH_;
    const size_t kbase = ((size_t)n * L_) * C_ + h * DH_;
    const size_t vbase = (size_t)n * C_ * L_ + (size_t)h * DH_ * L_;

    const int q = wid * 16 + i16;

    short8_t bq = *(const short8_t*)&Qws[qbase + (size_t)q * C_ + g * 8];

    #pragma unroll
    for (int p = 0; p < 4; ++p) {
        const int kg = (lane & 3) ^ ((lane >> 3) & 3);
        const int kr = wid * 64 + p * 16 + (lane >> 2);
        const u16* ksrc = Kws + kbase + (size_t)kr * C_ + kg * 8;
        __builtin_amdgcn_global_load_lds(AS1(ksrc),
            AS3(smem + wid * 4096 + p * 1024), 16, 0, 0);
        const int vd = wid * 8 + p * 2 + (lane >> 5);
        const u16* vsrc = Vws + vbase + (size_t)vd * L_ + ((lane & 31) ^ (vd & 7)) * 8;
        __builtin_amdgcn_global_load_lds(AS1(vsrc),
            AS3(smem + 16384 + wid * 4096 + p * 1024), 16, 0, 0);
    }
    __syncthreads();

    const int kgr = g ^ ((i16 >> 1) & 3);
    f32x4 s[16];
    #pragma unroll
    for (int nf = 0; nf < 16; ++nf) {
        short8_t a = *(const short8_t*)(smem + (nf * 16 + i16) * 64 + kgr * 16);
        f32x4 z = {0.f, 0.f, 0.f, 0.f};
        s[nf] = __builtin_amdgcn_mfma_f32_16x16x32_bf16(a, bq, z, 0, 0, 0);
    }

    float mm[16], sm[16];
    #pragma unroll
    for (int nf = 0; nf < 16; ++nf)
        mm[nf] = fmaxf(fmaxf(s[nf][0], s[nf][1]), fmaxf(s[nf][2], s[nf][3]));
    #pragma unroll
    for (int st = 8; st >= 1; st >>= 1)
        #pragma unroll
        for (int i = 0; i < 8; ++i)
            if (i < st) mm[i] = fmaxf(mm[i], mm[i + st]);
    float m = mm[0];
    m = fmaxf(m, __shfl_xor(m, 16));
    m = fmaxf(m, __shfl_xor(m, 32));

    const float K2 = 0.25506288f;  // log2(e) / sqrt(32)
    #pragma unroll
    for (int nf = 0; nf < 16; ++nf) {
        #pragma unroll
        for (int r = 0; r < 4; ++r) s[nf][r] = exp2f((s[nf][r] - m) * K2);
        sm[nf] = (s[nf][0] + s[nf][1]) + (s[nf][2] + s[nf][3]);
    }
    #pragma unroll
    for (int st = 8; st >= 1; st >>= 1)
        #pragma unroll
        for (int i = 0; i < 8; ++i)
            if (i < st) sm[i] += sm[i + st];
    float ssum = sm[0];
    ssum += __shfl_xor(ssum, 16);
    ssum += __shfl_xor(ssum, 32);
    const float pinv = 1.0f / ssum;

    __syncthreads();  // K dead -> P may alias

    f32x4 o0 = {0.f, 0.f, 0.f, 0.f}, o1 = {0.f, 0.f, 0.f, 0.f};
    const int e7 = i16 & 7;

    #pragma unroll
    for (int hb = 0; hb < 2; ++hb) {
        #pragma unroll
        for (int nfp = 0; nfp < 8; ++nfp) {
            const int nf = hb * 8 + nfp;
            #pragma unroll
            for (int w = 0; w < 2; ++w) {
                u32 pw = cvt_pk_bf16(s[nf][2 * w] * pinv, s[nf][2 * w + 1] * pinv);
                const int gran = (nfp * 2 + (g >> 1)) ^ e7;
                *(u32*)(smem + q * 256 + gran * 16 + ((g & 1) * 2 + w) * 4) = pw;
            }
        }
        __syncthreads();
        #pragma unroll
        for (int ks = 0; ks < 4; ++ks) {
            short8_t pb = *(const short8_t*)(smem + q * 256 + (((ks * 4 + g) ^ e7) * 16));
            const int vg = (((hb * 4 + ks) * 4 + g) ^ e7) * 16;
            short8_t va0 = *(const short8_t*)(smem + 16384 + i16 * 512 + vg);
            short8_t va1 = *(const short8_t*)(smem + 16384 + (16 + i16) * 512 + vg);
            o0 = __builtin_amdgcn_mfma_f32_16x16x32_bf16(va0, pb, o0, 0, 0, 0);
            o1 = __builtin_amdgcn_mfma_f32_16x16x32_bf16(va1, pb, o1, 0, 0, 0);
        }
        if (hb == 0) __syncthreads();
    }

    const size_t obase = ((size_t)n * C_ + h * DH_) * HW_ + pos0 + q;
    #pragma unroll
    for (int r = 0; r < 4; ++r) {
        const size_t oa = obase + (size_t)(g * 4 + r) * HW_;
        out[oa] = feature[oa] + o0[r];
        const size_t ob = obase + (size_t)(16 + g * 4 + r) * HW_;
        out[ob] = feature[ob] + o1[r];
    }
}

extern "C" void kernel_launch(void* const* d_in, const int* in_sizes, int n_in,
                              void* d_out, int out_size, void* d_ws, size_t ws_size,
                              hipStream_t stream)
{
    const float* feature = (const float*)d_in[0];
    const float* token   = (const float*)d_in[1];
    const float* wq      = (const float*)d_in[2];
    const float* bq      = (const float*)d_in[3];
    const float* wk      = (const float*)d_in[4];
    const float* bk      = (const float*)d_in[5];
    const float* wv      = (const float*)d_in[6];
    const float* bv      = (const float*)d_in[7];
    float* out = (float*)d_out;

    // d_ws: Q [16384][512] bf16 (16 MiB) | K (4 MiB) | Vt [n][d][l] (4 MiB)
    u16* Qws = (u16*)d_ws;
    u16* Kws = Qws + (size_t)N_ * HW_ * C_;
    u16* Vws = Kws + (size_t)N_ * L_ * C_;

    // d_out scratch (consumed before attn writes out):
    //   [0,16M): Ftb bf16 | [21M,+0.5M): wqb
    char* ob = (char*)d_out;
    u16* Ftb = (u16*)ob;
    u16* wqb = (u16*)(ob + (21u << 20));

    prep_kernel<<<dim3(2560), 256, 0, stream>>>(feature, token, wq, wk, wv,
                                                bk, bv, Ftb, wqb, Kws, Vws);
    gemm_q_kernel<<<dim3(1024), 256, 0, stream>>>(Ftb, wqb, bq, Qws);
    attn_kernel<<<dim3(16, 16, 16), 256, 0, stream>>>(Qws, Kws, Vws, feature, out);
}